// Round 9
// baseline (439.655 us; speedup 1.0000x reference)
//
#include <hip/hip_runtime.h>

#define NNODES 100000
#define NEDGES 3200000
#define NFEAT  512
#define NHID   16
#define NCLS   64
#define NB     391      // buckets of 256 nodes (bucket = dst>>8)
#define CAP    10240    // per-bucket edge capacity (mean 8192, sd ~90 -> +22 sigma)
#define EPB    8192     // edges per partition block (391 partition blocks)
#define GTPB   8        // gemm tiles (16 rows) per gemm block
#define NGB    782      // ceil(6250 tiles / 8)

typedef short bf16x8 __attribute__((ext_vector_type(8)));
typedef float f32x4  __attribute__((ext_vector_type(4)));

__device__ __forceinline__ short f2bf(float f) {
    unsigned u = __float_as_uint(f);
    return (short)((u + 0x7FFFu + ((u >> 16) & 1u)) >> 16);
}
__device__ __forceinline__ float bf2f(unsigned short u) {
    return __uint_as_float((unsigned)u << 16);
}

struct PartShared {                 // 55,892 B (R3's proven k_part layout)
    unsigned hist[NB];
    unsigned scn[512];
    unsigned cursor[NB];
    unsigned delta[NB];
    unsigned staged[EPB];
    unsigned short pbkt[EPB];
};
struct GemmShared { short w1t[16][520]; };  // 16,640 B
union FusedShared { PartShared p; GemmShared g; };

// ---- kA: blocks [0,NB) partition edges; blocks [NB,NB+NGB) x@W1 (unscaled). R8 verbatim.
__global__ __launch_bounds__(512) void k_fused1(const int* __restrict__ src,
                                                const int* __restrict__ dst,
                                                unsigned* __restrict__ gcnt,
                                                unsigned* __restrict__ part,
                                                const float* __restrict__ x,
                                                const float* __restrict__ w1,
                                                unsigned short* __restrict__ hs1) {
    __shared__ FusedShared sh;
    int t = threadIdx.x;
    if (blockIdx.x < NB) {
        int base = blockIdx.x * EPB;
        int nblk = min(EPB, NEDGES - base);
        for (int i = t; i < NB; i += 512) sh.p.hist[i] = 0;
        __syncthreads();
        unsigned pk[16]; unsigned short bk[16];
#pragma unroll
        for (int j = 0; j < 16; ++j) {
            int o = t + j * 512;
            if (o < nblk) {
                int s = src[base + o], d = dst[base + o];
                pk[j] = (unsigned)s | ((unsigned)(d & 255) << 17);
                bk[j] = (unsigned short)(d >> 8);
                atomicAdd(&sh.p.hist[bk[j]], 1u);
            } else bk[j] = 0xFFFFu;
        }
        __syncthreads();
        sh.p.scn[t] = (t < NB) ? sh.p.hist[t] : 0u;
        __syncthreads();
#pragma unroll
        for (int off = 1; off < 512; off <<= 1) {
            unsigned a = (t >= off) ? sh.p.scn[t - off] : 0u;
            __syncthreads();
            sh.p.scn[t] += a;
            __syncthreads();
        }
        for (int i = t; i < NB; i += 512) {
            unsigned h = sh.p.hist[i];
            unsigned ex = sh.p.scn[i] - h;
            sh.p.cursor[i] = ex;
            unsigned gb = h ? atomicAdd(&gcnt[i], h) : 0u;
            sh.p.delta[i] = (unsigned)i * CAP + gb - ex;
        }
        __syncthreads();
#pragma unroll
        for (int j = 0; j < 16; ++j) {
            if (bk[j] != 0xFFFFu) {
                unsigned p = atomicAdd(&sh.p.cursor[bk[j]], 1u);
                sh.p.staged[p] = pk[j];
                sh.p.pbkt[p] = bk[j];
            }
        }
        __syncthreads();
        for (int i = t; i < nblk; i += 512) {
            unsigned b = sh.p.pbkt[i];
            unsigned d = sh.p.delta[b] + (unsigned)i;
            if (d < (b + 1u) * CAP) part[d] = sh.p.staged[i];   // overflow guard
        }
    } else {
        for (int idx = t; idx < NFEAT * NHID; idx += 512) {
            int k = idx >> 4, n = idx & 15;
            sh.g.w1t[n][k] = f2bf(w1[idx]);
        }
        __syncthreads();
        int wave = t >> 6, lane = t & 63;
        int tile = (int)(blockIdx.x - NB) * GTPB + wave;
        if (tile >= NNODES / 16) return;
        int m = lane & 15, q = lane >> 4;
        const float* xrow = x + (size_t)(tile * 16 + m) * NFEAT + q * 8;
        const short* wrow = &sh.g.w1t[m][q * 8];
        f32x4 acc = {0.f, 0.f, 0.f, 0.f};
#pragma unroll
        for (int kb = 0; kb < NFEAT / 32; ++kb) {
            float4 a0 = *(const float4*)(xrow + kb * 32);
            float4 a1 = *(const float4*)(xrow + kb * 32 + 4);
            bf16x8 a;
            a[0] = f2bf(a0.x); a[1] = f2bf(a0.y); a[2] = f2bf(a0.z); a[3] = f2bf(a0.w);
            a[4] = f2bf(a1.x); a[5] = f2bf(a1.y); a[6] = f2bf(a1.z); a[7] = f2bf(a1.w);
            bf16x8 bfr = *(const bf16x8*)(wrow + kb * 32);
            acc = __builtin_amdgcn_mfma_f32_16x16x32_bf16(a, bfr, acc, 0, 0, 0);
        }
        unsigned short* outp = hs1 + (size_t)(tile * 16) * NHID;
#pragma unroll
        for (int r = 0; r < 4; ++r)
            outp[(q * 4 + r) * NHID + m] = (unsigned short)f2bf(acc[r]);
    }
}

// ---- kB1: per-bucket degree hist -> dinv; scale own hs1 rows in place. R8 verbatim.
__global__ __launch_bounds__(512) void k_scale(const unsigned* __restrict__ gcnt,
                                               const unsigned* __restrict__ part,
                                               float* __restrict__ dinv,
                                               unsigned short* __restrict__ hs1) {
    __shared__ unsigned hist[256];
    __shared__ float dl[256];
    int t = threadIdx.x, b = blockIdx.x;
    unsigned cb = min(gcnt[b], (unsigned)CAP);
    const unsigned* seg = part + (size_t)b * CAP;
    if (t < 256) hist[t] = 0;
    __syncthreads();
    for (unsigned i = t; i < cb; i += 512)
        atomicAdd(&hist[(seg[i] >> 17) & 255u], 1u);
    __syncthreads();
    if (t < 256) {
        dl[t] = rsqrtf((float)hist[t] + 1.f);               // +1 = self-loop
        int gn = b * 256 + t;
        if (gn < NNODES) dinv[gn] = dl[t];
    }
    __syncthreads();
    for (int i = t; i < 4096; i += 512) {                   // hs1[gn] *= dinv[gn]
        int nd = i >> 4, ff = i & 15;
        int gn = b * 256 + nd;
        if (gn < NNODES) {
            size_t ix = (size_t)gn * NHID + ff;
            hs1[ix] = (unsigned short)f2bf(bf2f(hs1[ix]) * dl[nd]);
        }
    }
}

// ---- kB2: fine sort in LDS + layer-1 aggregate, VECTORIZED lane-per-edge gather.
// One dwordx4 wave-load covers 32 edge rows (8x fewer VMEM instrs than 16-lane/edge).
__global__ __launch_bounds__(512) void k_sortagg1(const unsigned* __restrict__ gcnt,
                                                  unsigned* __restrict__ part,
                                                  unsigned* __restrict__ offs,
                                                  unsigned* __restrict__ cnt,
                                                  const unsigned short* __restrict__ hs1,
                                                  const float* __restrict__ b1,
                                                  unsigned short* __restrict__ hs2) {
    __shared__ unsigned staged[CAP];                        // 40 KB sorted src lists
    __shared__ unsigned hist[256], cum[256], cur[256];
    __shared__ float dl[256];
    __shared__ __align__(16) unsigned char wrows[8][1536];  // per-wave 32 rows x 48B pad
    int t = threadIdx.x, b = blockIdx.x;
    int lane = t & 63, wv = t >> 6;
    unsigned cb = min(gcnt[b], (unsigned)CAP);
    unsigned* seg = part + (size_t)b * CAP;
    if (t < 256) hist[t] = 0;
    __syncthreads();
    for (unsigned i = t; i < cb; i += 512)
        atomicAdd(&hist[(seg[i] >> 17) & 255u], 1u);
    __syncthreads();
    if (t < 256) cum[t] = hist[t];
    __syncthreads();
#pragma unroll
    for (int off = 1; off < 256; off <<= 1) {
        unsigned a = (t >= off && t < 256) ? cum[t - off] : 0u;
        __syncthreads();
        if (t < 256) cum[t] += a;
        __syncthreads();
    }
    if (t < 256) {
        unsigned ex = cum[t] - hist[t];
        cur[t] = ex;
        dl[t] = rsqrtf((float)hist[t] + 1.f);
        int node = b * 256 + t;
        if (node < NNODES) {
            offs[node] = (unsigned)b * CAP + ex;
            cnt[node] = hist[t];
        }
    }
    __syncthreads();
    for (unsigned i = t; i < cb; i += 512) {
        unsigned p = seg[i];
        unsigned r = atomicAdd(&cur[(p >> 17) & 255u], 1u);
        staged[r] = p & 0x1FFFFu;                           // sorted src only
    }
    __syncthreads();
    for (unsigned i = t; i < cb; i += 512)
        seg[i] = staged[i];                                 // sorted list for kC (coalesced)
    // ---- layer-1 aggregate: lane-per-edge rows -> LDS pad -> column reduce ----
    int er = lane >> 1, half = lane & 1;                    // 32 edge slots x 2 halves
    int c = lane & 7, g = lane >> 3;                        // 8 dword cols x 8 row groups
    unsigned char* wb = &wrows[wv][0];
    float b1v0 = b1[2 * c], b1v1 = b1[2 * c + 1];
    for (int nd = wv; nd < 256; nd += 8) {
        int gn = b * 256 + nd;
        if (gn >= NNODES) continue;
        int lstart = (int)(cum[nd] - hist[nd]);
        int deg = (int)hist[nd];
        float di = dl[nd];
        float v0 = 0.f, v1 = 0.f;
        int rounds = (deg + 31) >> 5, cl = deg - 1;
        for (int r = 0; r < rounds; ++r) {
            int jb = r * 32;
            unsigned e = staged[lstart + min(jb + er, cl)];
            uint4 row = ((const uint4*)(hs1 + (size_t)e * NHID))[half];
            *(uint4*)(wb + er * 48 + half * 16) = row;      // wave-own region: no barrier
#pragma unroll
            for (int k = 0; k < 4; ++k) {
                int rr = g * 4 + k;
                unsigned d = *(const unsigned*)(wb + rr * 48 + c * 4);
                bool ok = (jb + rr) < deg;
                v0 += ok ? bf2f((unsigned short)(d & 0xFFFFu)) : 0.f;
                v1 += ok ? bf2f((unsigned short)(d >> 16)) : 0.f;
            }
        }
        v0 += __shfl_xor(v0, 8);  v1 += __shfl_xor(v1, 8);
        v0 += __shfl_xor(v0, 16); v1 += __shfl_xor(v1, 16);
        v0 += __shfl_xor(v0, 32); v1 += __shfl_xor(v1, 32);
        unsigned su = ((const unsigned*)(hs1 + (size_t)gn * NHID))[c];
        float o0 = (v0 + bf2f((unsigned short)(su & 0xFFFFu))) * di + b1v0;
        float o1 = (v1 + bf2f((unsigned short)(su >> 16))) * di + b1v1;
        o0 = o0 > 0.f ? o0 : 0.f;
        o1 = o1 > 0.f ? o1 : 0.f;
        o0 *= di; o1 *= di;                                 // pre-scale for layer 2
        unsigned pw = (unsigned)(unsigned short)f2bf(o0) |
                      ((unsigned)(unsigned short)f2bf(o1) << 16);
        if (lane < 8) ((unsigned*)(hs2 + (size_t)gn * NHID))[c] = pw;
    }
}

// ---- kC: layer-2 aggregate (vectorized gather) + W2 matvec + b2 + log_softmax
__global__ __launch_bounds__(512) void k_out2v(const unsigned* __restrict__ offs,
                                               const unsigned* __restrict__ cnt,
                                               const unsigned* __restrict__ eb,
                                               const unsigned short* __restrict__ hs2,
                                               const float* __restrict__ dinv,
                                               const float* __restrict__ w2,
                                               const float* __restrict__ b2,
                                               float* __restrict__ out) {
    __shared__ __align__(16) unsigned char wrows[8][1536];
    int t = threadIdx.x;
    int lane = t & 63, wv = t >> 6;
    int er = lane >> 1, half = lane & 1;
    int c = lane & 7, g = lane >> 3;
    unsigned char* wb = &wrows[wv][0];
    float w2c[NHID];
#pragma unroll
    for (int k = 0; k < NHID; ++k) w2c[k] = w2[k * NCLS + lane];
    float bb = b2[lane];
    int nd0 = blockIdx.x * 128 + wv * 16;                   // 16 nodes per wave
    for (int i = 0; i < 16; ++i) {
        int gn = nd0 + i;
        if (gn >= NNODES) break;
        unsigned start = offs[gn];
        int deg = (int)cnt[gn];
        float di = dinv[gn];
        float v0 = 0.f, v1 = 0.f;
        int rounds = (deg + 31) >> 5, cl = deg - 1;
        for (int r = 0; r < rounds; ++r) {
            int jb = r * 32;
            unsigned e = eb[start + min(jb + er, cl)];
            uint4 row = ((const uint4*)(hs2 + (size_t)e * NHID))[half];
            *(uint4*)(wb + er * 48 + half * 16) = row;
#pragma unroll
            for (int k = 0; k < 4; ++k) {
                int rr = g * 4 + k;
                unsigned d = *(const unsigned*)(wb + rr * 48 + c * 4);
                bool ok = (jb + rr) < deg;
                v0 += ok ? bf2f((unsigned short)(d & 0xFFFFu)) : 0.f;
                v1 += ok ? bf2f((unsigned short)(d >> 16)) : 0.f;
            }
        }
        v0 += __shfl_xor(v0, 8);  v1 += __shfl_xor(v1, 8);
        v0 += __shfl_xor(v0, 16); v1 += __shfl_xor(v1, 16);
        v0 += __shfl_xor(v0, 32); v1 += __shfl_xor(v1, 32);
        unsigned su = ((const unsigned*)(hs2 + (size_t)gn * NHID))[c];
        float t0 = (v0 + bf2f((unsigned short)(su & 0xFFFFu))) * di;
        float t1 = (v1 + bf2f((unsigned short)(su >> 16))) * di;
        float logit = bb;
#pragma unroll
        for (int k = 0; k < 8; ++k) {
            logit += __shfl(t0, k) * w2c[2 * k];
            logit += __shfl(t1, k) * w2c[2 * k + 1];
        }
        float mx = logit;
#pragma unroll
        for (int off = 32; off > 0; off >>= 1) mx = fmaxf(mx, __shfl_xor(mx, off));
        float ex = __expf(logit - mx);
        float s = ex;
#pragma unroll
        for (int off = 32; off > 0; off >>= 1) s += __shfl_xor(s, off);
        out[(size_t)gn * NCLS + lane] = logit - mx - logf(s);
    }
}

extern "C" void kernel_launch(void* const* d_in, const int* in_sizes, int n_in,
                              void* d_out, int out_size, void* d_ws, size_t ws_size,
                              hipStream_t stream) {
    const float* x  = (const float*)d_in[0];   // f32 [100000,512]
    const int*   ei = (const int*)d_in[1];     // int32 [2,3200000]
    const float* w1 = (const float*)d_in[2];   // f32 [512,16]
    const float* b1 = (const float*)d_in[3];   // f32 [16]
    const float* w2 = (const float*)d_in[4];   // f32 [16,64]
    const float* b2 = (const float*)d_in[5];   // f32 [64]
    const int* src = ei;
    const int* dst = ei + NEDGES;

    char* ws = (char*)d_ws;
    unsigned* gcnt = (unsigned*)(ws + 0);          //     2,048 B
    unsigned* offs = (unsigned*)(ws + 2048);       //   400,000 B
    unsigned* cnt  = (unsigned*)(ws + 402048);     //   400,000 B
    float*    dinv = (float*)   (ws + 802048);     //   400,000 B
    unsigned short* hs1 = (unsigned short*)(ws + 1202048);  // 3,200,000 B (bf16)
    unsigned short* hs2 = (unsigned short*)(ws + 4402048);  // 3,200,000 B (bf16)
    unsigned* part = (unsigned*)(ws + 7602048);    // 16,015,360 B (total ~23.6 MB)

    hipMemsetAsync(gcnt, 0, 2048, stream);
    k_fused1  <<<NB + NGB, 512, 0, stream>>>(src, dst, gcnt, part, x, w1, hs1);
    k_scale   <<<NB, 512, 0, stream>>>(gcnt, part, dinv, hs1);
    k_sortagg1<<<NB, 512, 0, stream>>>(gcnt, part, offs, cnt, hs1, b1, hs2);
    k_out2v   <<<(NNODES + 127) / 128, 512, 0, stream>>>(offs, cnt, part, hs2, dinv, w2, b2, (float*)d_out);
}

// Round 10
// 422.246 us; speedup vs baseline: 1.0412x; 1.0412x over previous
//
#include <hip/hip_runtime.h>

#define NNODES 100000
#define NEDGES 3200000
#define NFEAT  512
#define NHID   16
#define NCLS   64
#define NB     782      // buckets of 128 nodes (bucket = dst>>7) -> 3.05 blocks/CU
#define CAP    5120     // per-bucket edge capacity (mean 4092, sd ~64 -> +16 sigma)
#define EPB    8192     // edges per partition block (391 partition blocks)
#define NPART  391
#define GTPB   8        // gemm tiles (16 rows) per gemm block
#define NGB    782      // ceil(6250 tiles / 8)

typedef short bf16x8 __attribute__((ext_vector_type(8)));
typedef float f32x4  __attribute__((ext_vector_type(4)));

__device__ __forceinline__ short f2bf(float f) {
    unsigned u = __float_as_uint(f);
    return (short)((u + 0x7FFFu + ((u >> 16) & 1u)) >> 16);
}
__device__ __forceinline__ float bf2f(unsigned short u) {
    return __uint_as_float((unsigned)u << 16);
}

struct PartShared {                 // 62,632 B
    unsigned hist[NB];
    unsigned scn[1024];             // two-slot scan (R0's proven pattern)
    unsigned cursor[NB];
    unsigned delta[NB];
    unsigned staged[EPB];
    unsigned short pbkt[EPB];
};
struct GemmShared { short w1t[16][520]; };  // 16,640 B
union FusedShared { PartShared p; GemmShared g; };

// ---- kA: blocks [0,NPART) partition edges into 782 buckets; blocks [NPART,..) x@W1.
__global__ __launch_bounds__(512) void k_fused1(const int* __restrict__ src,
                                                const int* __restrict__ dst,
                                                unsigned* __restrict__ gcnt,
                                                unsigned* __restrict__ part,
                                                const float* __restrict__ x,
                                                const float* __restrict__ w1,
                                                unsigned short* __restrict__ hs1) {
    __shared__ FusedShared sh;
    int t = threadIdx.x;
    if (blockIdx.x < NPART) {
        int base = blockIdx.x * EPB;
        int nblk = min(EPB, NEDGES - base);
        for (int i = t; i < NB; i += 512) sh.p.hist[i] = 0;
        __syncthreads();
        unsigned pk[16]; unsigned short bk[16];
#pragma unroll
        for (int j = 0; j < 16; ++j) {
            int o = t + j * 512;
            if (o < nblk) {
                int s = src[base + o], d = dst[base + o];
                pk[j] = (unsigned)s | ((unsigned)(d & 127) << 17);
                bk[j] = (unsigned short)(d >> 7);
                atomicAdd(&sh.p.hist[bk[j]], 1u);
            } else bk[j] = 0xFFFFu;
        }
        __syncthreads();
        // two-slot inclusive scan over 1024 padded slots
        sh.p.scn[t] = (t < NB) ? sh.p.hist[t] : 0u;
        sh.p.scn[t + 512] = (t + 512 < NB) ? sh.p.hist[t + 512] : 0u;
        __syncthreads();
#pragma unroll
        for (int off = 1; off < 1024; off <<= 1) {
            unsigned a = (t >= off) ? sh.p.scn[t - off] : 0u;
            unsigned b2 = (t + 512 >= off) ? sh.p.scn[t + 512 - off] : 0u;
            __syncthreads();
            sh.p.scn[t] += a;
            sh.p.scn[t + 512] += b2;
            __syncthreads();
        }
        for (int i = t; i < NB; i += 512) {
            unsigned h = sh.p.hist[i];
            unsigned ex = sh.p.scn[i] - h;
            sh.p.cursor[i] = ex;
            unsigned gb = h ? atomicAdd(&gcnt[i], h) : 0u;
            sh.p.delta[i] = (unsigned)i * CAP + gb - ex;
        }
        __syncthreads();
#pragma unroll
        for (int j = 0; j < 16; ++j) {
            if (bk[j] != 0xFFFFu) {
                unsigned p = atomicAdd(&sh.p.cursor[bk[j]], 1u);
                sh.p.staged[p] = pk[j];
                sh.p.pbkt[p] = bk[j];
            }
        }
        __syncthreads();
        for (int i = t; i < nblk; i += 512) {
            unsigned b = sh.p.pbkt[i];
            unsigned d = sh.p.delta[b] + (unsigned)i;
            if (d < (b + 1u) * CAP) part[d] = sh.p.staged[i];   // overflow guard
        }
    } else {
        for (int idx = t; idx < NFEAT * NHID; idx += 512) {
            int k = idx >> 4, n = idx & 15;
            sh.g.w1t[n][k] = f2bf(w1[idx]);
        }
        __syncthreads();
        int wave = t >> 6, lane = t & 63;
        int tile = (int)(blockIdx.x - NPART) * GTPB + wave;
        if (tile >= NNODES / 16) return;
        int m = lane & 15, q = lane >> 4;
        const float* xrow = x + (size_t)(tile * 16 + m) * NFEAT + q * 8;
        const short* wrow = &sh.g.w1t[m][q * 8];
        f32x4 acc = {0.f, 0.f, 0.f, 0.f};
#pragma unroll
        for (int kb = 0; kb < NFEAT / 32; ++kb) {
            float4 a0 = *(const float4*)(xrow + kb * 32);
            float4 a1 = *(const float4*)(xrow + kb * 32 + 4);
            bf16x8 a;
            a[0] = f2bf(a0.x); a[1] = f2bf(a0.y); a[2] = f2bf(a0.z); a[3] = f2bf(a0.w);
            a[4] = f2bf(a1.x); a[5] = f2bf(a1.y); a[6] = f2bf(a1.z); a[7] = f2bf(a1.w);
            bf16x8 bfr = *(const bf16x8*)(wrow + kb * 32);
            acc = __builtin_amdgcn_mfma_f32_16x16x32_bf16(a, bfr, acc, 0, 0, 0);
        }
        unsigned short* outp = hs1 + (size_t)(tile * 16) * NHID;
#pragma unroll
        for (int r = 0; r < 4; ++r)
            outp[(q * 4 + r) * NHID + m] = (unsigned short)f2bf(acc[r]);
    }
}

// ---- kB1: per-bucket degree hist -> dinv; scale own hs1 rows in place (128 nodes/bucket)
__global__ __launch_bounds__(512) void k_scale(const unsigned* __restrict__ gcnt,
                                               const unsigned* __restrict__ part,
                                               float* __restrict__ dinv,
                                               unsigned short* __restrict__ hs1) {
    __shared__ unsigned hist[128];
    __shared__ float dl[128];
    int t = threadIdx.x, b = blockIdx.x;
    unsigned cb = min(gcnt[b], (unsigned)CAP);
    const unsigned* seg = part + (size_t)b * CAP;
    if (t < 128) hist[t] = 0;
    __syncthreads();
    for (unsigned i = t; i < cb; i += 512)
        atomicAdd(&hist[(seg[i] >> 17) & 127u], 1u);
    __syncthreads();
    if (t < 128) {
        dl[t] = rsqrtf((float)hist[t] + 1.f);               // +1 = self-loop
        int gn = b * 128 + t;
        if (gn < NNODES) dinv[gn] = dl[t];
    }
    __syncthreads();
    for (int i = t; i < 2048; i += 512) {                   // hs1[gn] *= dinv[gn]
        int nd = i >> 4, ff = i & 15;
        int gn = b * 128 + nd;
        if (gn < NNODES) {
            size_t ix = (size_t)gn * NHID + ff;
            hs1[ix] = (unsigned short)f2bf(bf2f(hs1[ix]) * dl[nd]);
        }
    }
}

// ---- kB2: fine sort in LDS + layer-1 aggregate (R8's proven 2B-gather, batch-8)
__global__ __launch_bounds__(512) void k_sortagg1(const unsigned* __restrict__ gcnt,
                                                  unsigned* __restrict__ part,
                                                  unsigned* __restrict__ offs,
                                                  unsigned* __restrict__ cnt,
                                                  const unsigned short* __restrict__ hs1,
                                                  const float* __restrict__ b1,
                                                  unsigned short* __restrict__ hs2) {
    __shared__ unsigned staged[CAP];                        // 20 KB sorted src lists
    __shared__ unsigned hist[128], cum[128], cur[128];
    __shared__ float dl[128];
    int t = threadIdx.x, b = blockIdx.x;
    int lane = t & 63, wv = t >> 6;
    int f = lane & 15, slot = lane >> 4;
    unsigned cb = min(gcnt[b], (unsigned)CAP);
    unsigned* seg = part + (size_t)b * CAP;
    if (t < 128) hist[t] = 0;
    __syncthreads();
    for (unsigned i = t; i < cb; i += 512)
        atomicAdd(&hist[(seg[i] >> 17) & 127u], 1u);
    __syncthreads();
    if (t < 128) cum[t] = hist[t];
    __syncthreads();
#pragma unroll
    for (int off = 1; off < 128; off <<= 1) {
        unsigned a = (t >= off && t < 128) ? cum[t - off] : 0u;
        __syncthreads();
        if (t < 128) cum[t] += a;
        __syncthreads();
    }
    if (t < 128) {
        unsigned ex = cum[t] - hist[t];
        cur[t] = ex;
        dl[t] = rsqrtf((float)hist[t] + 1.f);
        int node = b * 128 + t;
        if (node < NNODES) {
            offs[node] = (unsigned)b * CAP + ex;
            cnt[node] = hist[t];
        }
    }
    __syncthreads();
    for (unsigned i = t; i < cb; i += 512) {
        unsigned p = seg[i];
        unsigned r = atomicAdd(&cur[(p >> 17) & 127u], 1u);
        staged[r] = p & 0x1FFFFu;                           // sorted src only
    }
    __syncthreads();
    for (unsigned i = t; i < cb; i += 512)
        seg[i] = staged[i];                                 // sorted list for kC (coalesced)
    // ---- layer-1 aggregate straight from LDS edge lists (hs1 pre-scaled by kB1) ----
    float b1f = b1[f];
    for (int nd = wv; nd < 128; nd += 8) {
        int gn = b * 128 + nd;
        if (gn >= NNODES) continue;
        int lstart = (int)(cum[nd] - hist[nd]);
        int deg = (int)hist[nd];
        float di = dl[nd];
        float acc = 0.f;
        int rounds = (deg + 31) >> 5, cl = deg - 1;
        for (int r = 0; r < rounds; ++r) {
            int jb = r * 32 + slot * 8;
            unsigned e[8];
#pragma unroll
            for (int u = 0; u < 8; ++u) e[u] = staged[lstart + min(jb + u, cl)];
            float a[8];
#pragma unroll
            for (int u = 0; u < 8; ++u) a[u] = bf2f(hs1[(size_t)e[u] * NHID + f]);
#pragma unroll
            for (int u = 0; u < 8; ++u) acc += (jb + u < deg) ? a[u] : 0.f;
        }
        acc += __shfl_xor(acc, 16);
        acc += __shfl_xor(acc, 32);
        float v = (acc + bf2f(hs1[(size_t)gn * NHID + f])) * di + b1f;
        v = v > 0.f ? v : 0.f;
        if (slot == 0) hs2[(size_t)gn * NHID + f] = (unsigned short)f2bf(v * di);
    }
}

// ---- kC: layer-2 aggregate + self + W2 matvec + b2 + log_softmax (R8 verbatim)
__global__ __launch_bounds__(256) void k_out2(const unsigned* __restrict__ offs,
                                              const unsigned* __restrict__ cnt,
                                              const unsigned* __restrict__ eb,
                                              const unsigned short* __restrict__ hs2,
                                              const float* __restrict__ dinv,
                                              const float* __restrict__ w2,
                                              const float* __restrict__ b2,
                                              float* __restrict__ out) {
    int tid = threadIdx.x;
    int node = blockIdx.x * 4 + (tid >> 6);
    int lane = tid & 63, f = lane & 15, slot = lane >> 4;
    unsigned start = offs[node];
    int deg = (int)cnt[node];
    float di = dinv[node];
    float w2c[NHID];
#pragma unroll
    for (int k = 0; k < NHID; ++k) w2c[k] = w2[k * NCLS + lane];
    float bb = b2[lane];
    float acc = 0.f;
    int rounds = (deg + 31) >> 5;
    int cl = deg - 1;
    for (int r = 0; r < rounds; ++r) {
        int jb = r * 32 + slot * 8;
        unsigned e[8];
#pragma unroll
        for (int u = 0; u < 8; ++u) e[u] = eb[start + min(jb + u, cl)];
        float a[8];
#pragma unroll
        for (int u = 0; u < 8; ++u) a[u] = bf2f(hs2[(size_t)e[u] * NHID + f]);
#pragma unroll
        for (int u = 0; u < 8; ++u) acc += (jb + u < deg) ? a[u] : 0.f;
    }
    acc += __shfl_xor(acc, 16);
    acc += __shfl_xor(acc, 32);
    float v = (acc + bf2f(hs2[(size_t)node * NHID + f])) * di;
    float logit = bb;
#pragma unroll
    for (int k = 0; k < NHID; ++k)
        logit += __shfl(v, k) * w2c[k];
    float mx = logit;
#pragma unroll
    for (int off = 32; off > 0; off >>= 1) mx = fmaxf(mx, __shfl_xor(mx, off));
    float ex = __expf(logit - mx);
    float s = ex;
#pragma unroll
    for (int off = 32; off > 0; off >>= 1) s += __shfl_xor(s, off);
    out[(size_t)node * NCLS + lane] = logit - mx - logf(s);
}

extern "C" void kernel_launch(void* const* d_in, const int* in_sizes, int n_in,
                              void* d_out, int out_size, void* d_ws, size_t ws_size,
                              hipStream_t stream) {
    const float* x  = (const float*)d_in[0];   // f32 [100000,512]
    const int*   ei = (const int*)d_in[1];     // int32 [2,3200000]
    const float* w1 = (const float*)d_in[2];   // f32 [512,16]
    const float* b1 = (const float*)d_in[3];   // f32 [16]
    const float* w2 = (const float*)d_in[4];   // f32 [16,64]
    const float* b2 = (const float*)d_in[5];   // f32 [64]
    const int* src = ei;
    const int* dst = ei + NEDGES;

    char* ws = (char*)d_ws;
    unsigned* gcnt = (unsigned*)(ws + 0);          //     4,096 B (782 used)
    unsigned* offs = (unsigned*)(ws + 4096);       //   400,000 B
    unsigned* cnt  = (unsigned*)(ws + 404096);     //   400,000 B
    float*    dinv = (float*)   (ws + 804096);     //   400,000 B
    unsigned short* hs1 = (unsigned short*)(ws + 1204096);  // 3,200,000 B (bf16)
    unsigned short* hs2 = (unsigned short*)(ws + 4404096);  // 3,200,000 B (bf16)
    unsigned* part = (unsigned*)(ws + 7604096);    // 16,015,360 B (total ~23.6 MB)

    hipMemsetAsync(gcnt, 0, 4096, stream);
    k_fused1  <<<NPART + NGB, 512, 0, stream>>>(src, dst, gcnt, part, x, w1, hs1);
    k_scale   <<<NB, 512, 0, stream>>>(gcnt, part, dinv, hs1);
    k_sortagg1<<<NB, 512, 0, stream>>>(gcnt, part, offs, cnt, hs1, b1, hs2);
    k_out2    <<<NNODES / 4, 256, 0, stream>>>(offs, cnt, part, hs2, dinv, w2, b2, (float*)d_out);
}